// Round 8
// baseline (333.707 us; speedup 1.0000x reference)
//
#include <hip/hip_runtime.h>
#include <hip/hip_bf16.h>

typedef short bf16x8 __attribute__((ext_vector_type(8)));
typedef short short8 __attribute__((ext_vector_type(8)));
typedef float f32x4  __attribute__((ext_vector_type(4)));

#define D     128
#define CH    32          // edges per wave-chunk = 2 16-row M-tiles
#define WPB   4           // waves per block
#define BLK   (WPB*64)    // 256 threads
#define NB    1024        // sort buckets (~98 nodes/bucket)
#define SBLK  256         // histo/scatter blocks
#define STHR  256
#define CONVB 1024        // conv blocks inside fused conv_histo

// f32 -> bf16 round-to-nearest-even (finite inputs)
__device__ __forceinline__ short f2bf(float f) {
    unsigned u = __float_as_uint(f);
    u = (u + 0x7fffu + ((u >> 16) & 1u)) >> 16;
    return (short)u;
}
__device__ __forceinline__ float bf2f(short s) {
    return __uint_as_float(((unsigned)(unsigned short)s) << 16);
}

// LDS byte offset for W1^T [row][128 bf16], XOR-swizzled (16B-granular, G4).
__device__ __forceinline__ int swz(int row, int intra) {
    return (row << 8) + (intra ^ ((row & 7) << 4));
}

// ---- prep: swizzled W1^T bf16 image (32 KB) ----
__global__ void prep_w1(const float* __restrict__ W1, short* __restrict__ ws) {
    const int idx = blockIdx.x * 256 + threadIdx.x;   // 64 x 256 = 16384
    const int k = idx >> 7, c = idx & 127;            // W1 is [k][c]
    ws[((c << 8) + ((2 * k) ^ ((c & 7) << 4))) >> 1] = f2bf(W1[idx]);
}

// ---- fused prep: blocks [0,CONVB) convert f32->bf16 (NT reads, less L3
// churn); blocks [CONVB,CONVB+SBLK) histogram edges by left-node bucket.
__global__ __launch_bounds__(STHR)
void conv_histo(const float* __restrict__ l, const float* __restrict__ r,
                short* __restrict__ lb, short* __restrict__ rb,
                int n8l, int n8r,
                const int* __restrict__ pairs, int E, float scale,
                int* __restrict__ counts, int* __restrict__ bases) {
    __shared__ int h[NB];
    if ((int)blockIdx.x < CONVB) {
        int i = blockIdx.x * STHR + threadIdx.x;
        const int tot = n8l + n8r;
        for (; i < tot; i += CONVB * STHR) {
            const float* s; short* d; int j;
            if (i < n8l) { s = l; d = lb; j = i; }
            else         { s = r; d = rb; j = i - n8l; }
            const f32x4 a = __builtin_nontemporal_load((const f32x4*)s + 2 * j);
            const f32x4 b = __builtin_nontemporal_load((const f32x4*)s + 2 * j + 1);
            short8 o;
            o[0]=f2bf(a[0]); o[1]=f2bf(a[1]); o[2]=f2bf(a[2]); o[3]=f2bf(a[3]);
            o[4]=f2bf(b[0]); o[5]=f2bf(b[1]); o[6]=f2bf(b[2]); o[7]=f2bf(b[3]);
            ((short8*)d)[j] = o;
        }
    } else {
        const int bb = blockIdx.x - CONVB;
        for (int x = threadIdx.x; x < NB; x += STHR) h[x] = 0;
        __syncthreads();
        const int epb = (E + SBLK - 1) / SBLK;
        const int lo = bb * epb, hi = min(lo + epb, E);
        for (int e = lo + threadIdx.x; e < hi; e += STHR)
            atomicAdd(&h[min(NB - 1, (int)((float)pairs[e] * scale))], 1);
        __syncthreads();
        for (int x = threadIdx.x; x < NB; x += STHR) {
            const int v = h[x];
            if (v) bases[bb * NB + x] = atomicAdd(&counts[x], v);
        }
    }
}

// ---- sort pass 2: exclusive scan of NB=1024 bucket counts, 1 block ----
__global__ __launch_bounds__(512)
void bucket_scan(int* __restrict__ counts) {
    __shared__ int a[512], b[512];
    const int t = threadIdx.x;
    const int c0 = counts[2 * t], c1 = counts[2 * t + 1];
    a[t] = c0 + c1;
    __syncthreads();
    int* src = a; int* dst = b;
    for (int off = 1; off < 512; off <<= 1) {
        int v = src[t];
        if (t >= off) v += src[t - off];
        __syncthreads();
        dst[t] = v;
        __syncthreads();
        int* tmp = src; src = dst; dst = tmp;
    }
    const int excl = src[t] - (c0 + c1);
    counts[2 * t]     = excl;
    counts[2 * t + 1] = excl + c0;
}

// ---- sort pass 3: scatter (i0,i1,eid) records into bucket order ----
__global__ __launch_bounds__(STHR)
void edge_scatter(const int* __restrict__ pairs, int E, float scale,
                  const int* __restrict__ starts, const int* __restrict__ bases,
                  int4* __restrict__ recs) {
    __shared__ int rk[NB];
    for (int x = threadIdx.x; x < NB; x += STHR) rk[x] = 0;
    __syncthreads();
    const int epb = (E + SBLK - 1) / SBLK;
    const int lo = blockIdx.x * epb, hi = min(lo + epb, E);
    for (int e = lo + threadIdx.x; e < hi; e += STHR) {
        const int i0 = pairs[e], i1 = pairs[E + e];
        const int bkt = min(NB - 1, (int)((float)i0 * scale));
        const int rr = atomicAdd(&rk[bkt], 1);
        recs[starts[bkt] + bases[blockIdx.x * NB + bkt] + rr] =
            make_int4(i0, i1, e, 0);
    }
}

// MODE 0: f32 unsorted. MODE 1: bf16 unsorted. MODE 2: bf16 sorted.
// A-fragments built DIRECTLY from global gathers (no LDS x-stage); each B
// ds_read feeds two MFMAs (M=32/wave) -> LDS pipe ~1KB/edge, under byte floor.
template <int MODE>
__global__ __launch_bounds__(BLK, 3)
void edge_decoder_kernel(const float* __restrict__ left,
                         const float* __restrict__ right,
                         const short* __restrict__ leftb,
                         const short* __restrict__ rightb,
                         const int* __restrict__ pairs,
                         const int4* __restrict__ recs,
                         const short* __restrict__ w1ws,
                         const float* __restrict__ b1,
                         const float* __restrict__ W2,
                         const float* __restrict__ b2,
                         float* __restrict__ out, int E)
{
    __shared__ char w1t[32768];      // W1^T bf16, swizzled (only LDS use)

    const int tid  = threadIdx.x;
    const int lane = tid & 63;
    const int wid  = tid >> 6;
    const int lg   = lane >> 4;      // lanegroup 0..3 (k-offset selector)
    const int lm   = lane & 15;      // edge slot within M-tile / hidden col
    const int l32  = lane & 31;

    for (int j = tid; j < 2048; j += BLK)           // linear, conflict-free
        *(f32x4*)(w1t + j * 16) = ((const f32x4*)w1ws)[j];

    float b1v[8], w2v[8];
    #pragma unroll
    for (int ct = 0; ct < 8; ++ct) {
        b1v[ct] = b1[ct * 16 + lm];
        w2v[ct] = W2[ct * 16 + lm];
    }
    const float b2s = b2[0];
    __syncthreads();

    const int chunks = (E + CH - 1) / CH;
    int c, hiC, stepC;
    if (MODE == 2) {                 // contiguous range per block: locality
        const int cpb = (chunks + gridDim.x - 1) / gridDim.x;
        c = blockIdx.x * cpb + wid;
        hiC = min(blockIdx.x * cpb + cpb, chunks);
        stepC = WPB;
    } else {
        c = blockIdx.x * WPB + wid;
        hiC = chunks;
        stepC = gridDim.x * WPB;
    }
    if (c >= hiC) return;

    // lanes 0-31 hold this chunk's 32 edge records (32-63 duplicate)
    auto ld = [&](int cc, int& i0v, int& i1v, int& eidv) {
        const int slot = cc * CH + l32;
        if (MODE == 2) {
            if (slot < E) {
                const int4 rc = recs[slot];
                i0v = rc.x; i1v = rc.y; eidv = rc.z;
            } else { i0v = 0; i1v = 0; eidv = -1; }
        } else {
            eidv = (slot < E) ? slot : -1;
            const int e0 = (slot < E) ? slot : E - 1;
            i0v = pairs[e0]; i1v = pairs[E + e0];
        }
    };

    int i0v, i1v, eidv;
    ld(c, i0v, i1v, eidv);

    while (true) {
        const int cn = c + stepC;
        const bool has = cn < hiC;
        int i0n = 0, i1n = 0, eidn = -1;
        if (has) ld(cn, i0n, i1n, eidn);   // prefetch next chunk's records

        // this lane's edge indices for its two M-tiles (4 shuffles/chunk)
        const int iL0 = __shfl(i0v, lm);
        const int iL1 = __shfl(i0v, 16 + lm);
        const int iR0 = __shfl(i1v, lm);
        const int iR1 = __shfl(i1v, 16 + lm);

        // ---- gather burst -> A-fragments in registers ----
        // A lane-map: row = lm, k = kt*32 + lg*8 + e  == 16B at row*256B +
        // (kt*32+lg*8)*2B. Whole rows covered within the burst (r3 lesson).
        bf16x8 afr[2][4];
        if (MODE >= 1) {
            const short* lp0 = leftb  + iL0 * D + lg * 8;
            const short* lp1 = leftb  + iL1 * D + lg * 8;
            const short* rp0 = rightb + iR0 * D + lg * 8;
            const short* rp1 = rightb + iR1 * D + lg * 8;
            short8 lv[2][4], rv[2][4];
            #pragma unroll
            for (int kt = 0; kt < 4; ++kt) {
                lv[0][kt] = *(const short8*)(lp0 + kt * 32);
                lv[1][kt] = *(const short8*)(lp1 + kt * 32);
                rv[0][kt] = *(const short8*)(rp0 + kt * 32);
                rv[1][kt] = *(const short8*)(rp1 + kt * 32);
            }
            #pragma unroll
            for (int mt = 0; mt < 2; ++mt)
                #pragma unroll
                for (int kt = 0; kt < 4; ++kt)
                    #pragma unroll
                    for (int e = 0; e < 8; ++e)
                        afr[mt][kt][e] =
                            f2bf(bf2f(lv[mt][kt][e]) * bf2f(rv[mt][kt][e]));
        } else {
            const float* lp0 = left  + iL0 * D + lg * 8;
            const float* lp1 = left  + iL1 * D + lg * 8;
            const float* rp0 = right + iR0 * D + lg * 8;
            const float* rp1 = right + iR1 * D + lg * 8;
            #pragma unroll
            for (int mt = 0; mt < 2; ++mt) {
                const float* lp = mt ? lp1 : lp0;
                const float* rp = mt ? rp1 : rp0;
                #pragma unroll
                for (int kt = 0; kt < 4; ++kt) {
                    const f32x4 la = *(const f32x4*)(lp + kt * 32);
                    const f32x4 lb2 = *(const f32x4*)(lp + kt * 32 + 4);
                    const f32x4 ra = *(const f32x4*)(rp + kt * 32);
                    const f32x4 rb2 = *(const f32x4*)(rp + kt * 32 + 4);
                    #pragma unroll
                    for (int e = 0; e < 4; ++e) {
                        afr[mt][kt][e]     = f2bf(la[e] * ra[e]);
                        afr[mt][kt][e + 4] = f2bf(lb2[e] * rb2[e]);
                    }
                }
            }
        }

        // ---- MFMA: each B ds_read feeds both M-tiles ----
        f32x4 acc[2][8];
        #pragma unroll
        for (int mt = 0; mt < 2; ++mt)
            #pragma unroll
            for (int ct = 0; ct < 8; ++ct)
                acc[mt][ct] = (f32x4){0.f, 0.f, 0.f, 0.f};

        #pragma unroll
        for (int kt = 0; kt < 4; ++kt)
            #pragma unroll
            for (int ct = 0; ct < 8; ++ct) {
                const bf16x8 bfr = *(const bf16x8*)(
                    w1t + swz(ct * 16 + lm, kt * 64 + lg * 16));
                acc[0][ct] = __builtin_amdgcn_mfma_f32_16x16x32_bf16(
                    afr[0][kt], bfr, acc[0][ct], 0, 0, 0);
                acc[1][ct] = __builtin_amdgcn_mfma_f32_16x16x32_bf16(
                    afr[1][kt], bfr, acc[1][ct], 0, 0, 0);
            }

        // ---- bias + ReLU + dot(W2) + 16-lane reduce + sigmoid ----
        // C-frag layout (HW-measured): col = lane&15, row = (lane>>4)*4+reg.
        #pragma unroll
        for (int mt = 0; mt < 2; ++mt) {
            float p0 = 0.f, p1 = 0.f, p2 = 0.f, p3 = 0.f;
            #pragma unroll
            for (int ct = 0; ct < 8; ++ct) {
                float h0 = fmaxf(acc[mt][ct][0] + b1v[ct], 0.f);
                float h1 = fmaxf(acc[mt][ct][1] + b1v[ct], 0.f);
                float h2 = fmaxf(acc[mt][ct][2] + b1v[ct], 0.f);
                float h3 = fmaxf(acc[mt][ct][3] + b1v[ct], 0.f);
                p0 = fmaf(h0, w2v[ct], p0);
                p1 = fmaf(h1, w2v[ct], p1);
                p2 = fmaf(h2, w2v[ct], p2);
                p3 = fmaf(h3, w2v[ct], p3);
            }
            #pragma unroll
            for (int s = 1; s < 16; s <<= 1) {
                p0 += __shfl_xor(p0, s);
                p1 += __shfl_xor(p1, s);
                p2 += __shfl_xor(p2, s);
                p3 += __shfl_xor(p3, s);
            }
            const int myeid = __shfl(eidv, mt * 16 + lg * 4 + (lm & 3));
            if (lm < 4 && myeid >= 0) {
                const float pv = (lm & 2) ? ((lm & 1) ? p3 : p2)
                                          : ((lm & 1) ? p1 : p0);
                out[myeid] = 1.f / (1.f + __expf(-(pv + b2s)));
            }
        }

        if (!has) break;
        c = cn; i0v = i0n; i1v = i1n; eidv = eidn;
    }
}

extern "C" void kernel_launch(void* const* d_in, const int* in_sizes, int n_in,
                              void* d_out, int out_size, void* d_ws, size_t ws_size,
                              hipStream_t stream) {
    const float* left  = (const float*)d_in[0];
    const float* right = (const float*)d_in[1];
    const int*   pairs = (const int*)d_in[2];
    const float* W1    = (const float*)d_in[3];
    const float* b1    = (const float*)d_in[4];
    const float* W2    = (const float*)d_in[5];
    const float* b2    = (const float*)d_in[6];
    float* out = (float*)d_out;

    const int E  = in_sizes[2] / 2;                // pairs is [2][E]
    const int nn = in_sizes[0] / D;                // node count
    const int chunks = (E + CH - 1) / CH;
    const float scale = (float)NB / (float)nn;

    char* const ws = (char*)d_ws;
    const size_t offL   = 32768;
    const size_t szL    = (size_t)in_sizes[0] * 2;
    const size_t offR   = offL + szL;
    const size_t szR    = (size_t)in_sizes[1] * 2;
    const size_t offCnt = offR + szR;
    const size_t offBas = offCnt + (size_t)NB * 4;
    const size_t offRec = offBas + (size_t)SBLK * NB * 4;
    const size_t needSort = offRec + (size_t)chunks * CH * 16;
    const size_t needBf   = offCnt;

    short* const w1img  = (short*)ws;
    short* const leftb  = (short*)(ws + offL);
    short* const rightb = (short*)(ws + offR);
    int*   const counts = (int*)(ws + offCnt);
    int*   const bases  = (int*)(ws + offBas);
    int4*  const recs   = (int4*)(ws + offRec);

    prep_w1<<<64, 256, 0, stream>>>(W1, w1img);

    if (ws_size >= needSort) {
        hipMemsetAsync(counts, 0, NB * 4, stream);
        conv_histo<<<CONVB + SBLK, STHR, 0, stream>>>(
            left, right, leftb, rightb, in_sizes[0] / 8, in_sizes[1] / 8,
            pairs, E, scale, counts, bases);
        bucket_scan<<<1, 512, 0, stream>>>(counts);
        edge_scatter<<<SBLK, STHR, 0, stream>>>(pairs, E, scale, counts,
                                                bases, recs);
        edge_decoder_kernel<2><<<768, BLK, 0, stream>>>(
            left, right, leftb, rightb, pairs, recs, w1img, b1, W2, b2, out, E);
    } else if (ws_size >= needBf) {
        conv_histo<<<CONVB, STHR, 0, stream>>>(
            left, right, leftb, rightb, in_sizes[0] / 8, in_sizes[1] / 8,
            pairs, E, scale, counts, bases);
        int blocks = 768;
        const int need = (chunks + WPB - 1) / WPB;
        if (need < blocks) blocks = need;
        edge_decoder_kernel<1><<<blocks, BLK, 0, stream>>>(
            left, right, leftb, rightb, pairs, recs, w1img, b1, W2, b2, out, E);
    } else {
        int blocks = 768;
        const int need = (chunks + WPB - 1) / WPB;
        if (need < blocks) blocks = need;
        edge_decoder_kernel<0><<<blocks, BLK, 0, stream>>>(
            left, right, leftb, rightb, pairs, recs, w1img, b1, W2, b2, out, E);
    }
}

// Round 9
// 158.999 us; speedup vs baseline: 2.0988x; 2.0988x over previous
//
#include <hip/hip_runtime.h>
#include <hip/hip_bf16.h>

typedef short bf16x8 __attribute__((ext_vector_type(8)));
typedef short short8 __attribute__((ext_vector_type(8)));
typedef float f32x4  __attribute__((ext_vector_type(4)));

#define D     128
#define CH    32          // edges per wave-chunk = 2 M-tiles; B reads amortized 2x
#define WPB   6           // waves per block
#define BLK   (WPB*64)    // 384 threads
#define NB    1024        // sort buckets (~98 nodes/bucket)
#define SBLK  256         // histo/scatter blocks
#define CONVB 1024        // conv blocks in fused scatter_conv

// f32 -> bf16 round-to-nearest-even (finite inputs)
__device__ __forceinline__ short f2bf(float f) {
    unsigned u = __float_as_uint(f);
    u = (u + 0x7fffu + ((u >> 16) & 1u)) >> 16;
    return (short)u;
}
__device__ __forceinline__ float bf2f(short s) {
    return __uint_as_float(((unsigned)(unsigned short)s) << 16);
}

// LDS byte offset for [row][128 bf16], XOR-swizzled (16B-granular, G4).
__device__ __forceinline__ int swz(int row, int intra) {
    return (row << 8) + (intra ^ ((row & 7) << 4));
}

// ---- prep: swizzled W1^T bf16 image (32 KB) ----
__global__ void prep_w1(const float* __restrict__ W1, short* __restrict__ ws) {
    const int idx = blockIdx.x * 256 + threadIdx.x;   // 64 x 256 = 16384
    const int k = idx >> 7, c = idx & 127;            // W1 is [k][c]
    ws[((c << 8) + ((2 * k) ^ ((c & 7) << 4))) >> 1] = f2bf(W1[idx]);
}

// ---- sort pass 1: per-block LDS histogram + global reservation ----
__global__ __launch_bounds__(256)
void edge_histo(const int* __restrict__ pairs, int E, float scale,
                int* __restrict__ counts, int* __restrict__ bases) {
    __shared__ int h[NB];
    for (int x = threadIdx.x; x < NB; x += 256) h[x] = 0;
    __syncthreads();
    const int epb = (E + SBLK - 1) / SBLK;
    const int lo = blockIdx.x * epb, hi = min(lo + epb, E);
    for (int e = lo + threadIdx.x; e < hi; e += 256)
        atomicAdd(&h[min(NB - 1, (int)((float)pairs[e] * scale))], 1);
    __syncthreads();
    for (int x = threadIdx.x; x < NB; x += 256) {
        const int v = h[x];
        if (v) bases[blockIdx.x * NB + x] = atomicAdd(&counts[x], v);
    }
}

// ---- sort pass 2: exclusive scan of NB=1024 bucket counts, 1 block ----
__global__ __launch_bounds__(512)
void bucket_scan(int* __restrict__ counts) {
    __shared__ int a[512], b[512];
    const int t = threadIdx.x;
    const int c0 = counts[2 * t], c1 = counts[2 * t + 1];
    a[t] = c0 + c1;
    __syncthreads();
    int* src = a; int* dst = b;
    for (int off = 1; off < 512; off <<= 1) {
        int v = src[t];
        if (t >= off) v += src[t - off];
        __syncthreads();
        dst[t] = v;
        __syncthreads();
        int* tmp = src; src = dst; dst = tmp;
    }
    const int excl = src[t] - (c0 + c1);
    counts[2 * t]     = excl;
    counts[2 * t + 1] = excl + c0;
}

// ---- fused: blocks [0,cbase) scatter records; rest convert f32->bf16.
// scatter and conv are independent -> they overlap in one dispatch.
__global__ __launch_bounds__(256)
void scatter_conv(const int* __restrict__ pairs, int E, float scale,
                  const int* __restrict__ starts, const int* __restrict__ bases,
                  int4* __restrict__ recs,
                  const float* __restrict__ l, const float* __restrict__ r,
                  short* __restrict__ lb, short* __restrict__ rb,
                  int n8l, int n8r, int cbase) {
    __shared__ int rk[NB];
    if ((int)blockIdx.x < cbase) {
        for (int x = threadIdx.x; x < NB; x += 256) rk[x] = 0;
        __syncthreads();
        const int epb = (E + SBLK - 1) / SBLK;
        const int lo = blockIdx.x * epb, hi = min(lo + epb, E);
        for (int e = lo + threadIdx.x; e < hi; e += 256) {
            const int i0 = pairs[e], i1 = pairs[E + e];
            const int bkt = min(NB - 1, (int)((float)i0 * scale));
            const int rr = atomicAdd(&rk[bkt], 1);
            recs[starts[bkt] + bases[blockIdx.x * NB + bkt] + rr] =
                make_int4(i0, i1, e, 0);
        }
    } else {
        const int nconv = gridDim.x - cbase;
        int i = (blockIdx.x - cbase) * 256 + threadIdx.x;
        const int tot = n8l + n8r;
        for (; i < tot; i += nconv * 256) {
            const float* s; short* d; int j;
            if (i < n8l) { s = l; d = lb; j = i; }
            else         { s = r; d = rb; j = i - n8l; }
            const f32x4 a = __builtin_nontemporal_load((const f32x4*)s + 2 * j);
            const f32x4 b = __builtin_nontemporal_load((const f32x4*)s + 2 * j + 1);
            short8 o;
            o[0]=f2bf(a[0]); o[1]=f2bf(a[1]); o[2]=f2bf(a[2]); o[3]=f2bf(a[3]);
            o[4]=f2bf(b[0]); o[5]=f2bf(b[1]); o[6]=f2bf(b[2]); o[7]=f2bf(b[3]);
            ((short8*)d)[j] = o;
        }
    }
}

// MODE 0: f32 unsorted. MODE 1: bf16 unsorted. MODE 2: bf16 sorted.
// Gather: whole-row single-instruction reads (r3/r8 lesson), LDS x-stage.
// CH=32 via two 16-edge rounds into ONE 4KB wave-private buffer; each B
// ds_read_b128 feeds 2 MFMAs -> LDS ~1.5KB/edge, under the byte floor.
template <int MODE>
__global__ __launch_bounds__(BLK, 3)
void edge_decoder_kernel(const float* __restrict__ left,
                         const float* __restrict__ right,
                         const short* __restrict__ leftb,
                         const short* __restrict__ rightb,
                         const int* __restrict__ pairs,
                         const int4* __restrict__ recs,
                         const short* __restrict__ w1ws,
                         const float* __restrict__ b1,
                         const float* __restrict__ W2,
                         const float* __restrict__ b2,
                         float* __restrict__ out, int E)
{
    __shared__ char smem[32768 + WPB * 4096];                   // 56 KB
    char* const w1t = smem;
    char* const xls = smem + 32768 + (threadIdx.x >> 6) * 4096; // wave-private

    const int tid  = threadIdx.x;
    const int lane = tid & 63;
    const int wid  = tid >> 6;
    const int lg   = lane >> 4;      // lanegroup 0..3
    const int lm   = lane & 15;
    const int half = lane >> 5;
    const int l32  = lane & 31;

    for (int j = tid; j < 2048; j += BLK)           // linear, conflict-free
        *(f32x4*)(w1t + j * 16) = ((const f32x4*)w1ws)[j];

    float b1v[8], w2v[8];
    #pragma unroll
    for (int ct = 0; ct < 8; ++ct) {
        b1v[ct] = b1[ct * 16 + lm];
        w2v[ct] = W2[ct * 16 + lm];
    }
    const float b2s = b2[0];
    __syncthreads();

    const int chunks = (E + CH - 1) / CH;
    int c, hiC, stepC;
    if (MODE == 2) {                 // contiguous range per block: locality
        const int cpb = (chunks + gridDim.x - 1) / gridDim.x;
        c = blockIdx.x * cpb + wid;
        hiC = min(blockIdx.x * cpb + cpb, chunks);
        stepC = WPB;
    } else {
        c = blockIdx.x * WPB + wid;
        hiC = chunks;
        stepC = gridDim.x * WPB;
    }
    if (c >= hiC) return;

    // lanes 0-31 hold this chunk's 32 edge records (32-63 duplicate)
    auto ld = [&](int cc, int& i0v, int& i1v, int& eidv) {
        const int slot = cc * CH + l32;
        if (MODE == 2) {
            if (slot < E) {
                const int4 rc = recs[slot];
                i0v = rc.x; i1v = rc.y; eidv = rc.z;
            } else { i0v = 0; i1v = 0; eidv = -1; }
        } else {
            eidv = (slot < E) ? slot : -1;
            const int e0 = (slot < E) ? slot : E - 1;
            i0v = pairs[e0]; i1v = pairs[E + e0];
        }
    };

    int i0v, i1v, eidv;
    ld(c, i0v, i1v, eidv);

    while (true) {
        const int cn = c + stepC;
        const bool has = cn < hiC;
        int i0n = 0, i1n = 0, eidn = -1;
        if (has) ld(cn, i0n, i1n, eidn);   // prefetch next chunk's records

        bf16x8 afr[2][4];
        #pragma unroll
        for (int mt = 0; mt < 2; ++mt) {
            if (MODE >= 1) {
                // bf16: 16B/lane, 16 lanes/row -> 4 whole rows/instr, burst
                const int q  = lane >> 4;
                const int lq = lane & 15;
                short8 lv[4], rv[4];
                #pragma unroll
                for (int j = 0; j < 4; ++j) {
                    const int iL = __shfl(i0v, mt * 16 + 4 * j + q);
                    lv[j] = *(const short8*)(leftb + iL * D + lq * 8);
                }
                #pragma unroll
                for (int j = 0; j < 4; ++j) {
                    const int iR = __shfl(i1v, mt * 16 + 4 * j + q);
                    rv[j] = *(const short8*)(rightb + iR * D + lq * 8);
                }
                #pragma unroll
                for (int j = 0; j < 4; ++j) {
                    short8 xb;
                    #pragma unroll
                    for (int e = 0; e < 8; ++e)
                        xb[e] = f2bf(bf2f(lv[j][e]) * bf2f(rv[j][e]));
                    *(short8*)(xls + swz(4 * j + q, lq * 16)) = xb;
                }
            } else {
                // f32: 2 whole rows/instr via float4, burst
                float4 lv[8], rv[8];
                #pragma unroll
                for (int j = 0; j < 8; ++j) {
                    const int eoff = 2 * j + half;
                    const int iL = __shfl(i0v, mt * 16 + eoff);
                    const int iR = __shfl(i1v, mt * 16 + eoff);
                    lv[j] = *(const float4*)(left  + iL * D + l32 * 4);
                    rv[j] = *(const float4*)(right + iR * D + l32 * 4);
                }
                #pragma unroll
                for (int j = 0; j < 8; ++j) {
                    const int eoff = 2 * j + half;
                    short4 xb;
                    xb.x = f2bf(lv[j].x * rv[j].x);
                    xb.y = f2bf(lv[j].y * rv[j].y);
                    xb.z = f2bf(lv[j].z * rv[j].z);
                    xb.w = f2bf(lv[j].w * rv[j].w);
                    *(short4*)(xls + swz(eoff, l32 * 8)) = xb;
                }
            }
            // A-frags for this M-tile (wave-private buffer, no barrier;
            // compiler inserts lgkmcnt between ds_write and ds_read)
            #pragma unroll
            for (int kt = 0; kt < 4; ++kt)
                afr[mt][kt] = *(const bf16x8*)(xls + swz(lm, kt * 64 + lg * 16));
        }

        // ---- MFMA: each B ds_read feeds both M-tiles ----
        f32x4 acc[2][8];
        #pragma unroll
        for (int mt = 0; mt < 2; ++mt)
            #pragma unroll
            for (int ct = 0; ct < 8; ++ct)
                acc[mt][ct] = (f32x4){0.f, 0.f, 0.f, 0.f};

        #pragma unroll
        for (int kt = 0; kt < 4; ++kt)
            #pragma unroll
            for (int ct = 0; ct < 8; ++ct) {
                const bf16x8 bfr = *(const bf16x8*)(
                    w1t + swz(ct * 16 + lm, kt * 64 + lg * 16));
                acc[0][ct] = __builtin_amdgcn_mfma_f32_16x16x32_bf16(
                    afr[0][kt], bfr, acc[0][ct], 0, 0, 0);
                acc[1][ct] = __builtin_amdgcn_mfma_f32_16x16x32_bf16(
                    afr[1][kt], bfr, acc[1][ct], 0, 0, 0);
            }

        // ---- bias + ReLU + dot(W2) + 16-lane reduce + sigmoid ----
        // C-frag layout (HW-measured): col = lane&15, row = (lane>>4)*4+reg.
        #pragma unroll
        for (int mt = 0; mt < 2; ++mt) {
            float p0 = 0.f, p1 = 0.f, p2 = 0.f, p3 = 0.f;
            #pragma unroll
            for (int ct = 0; ct < 8; ++ct) {
                float h0 = fmaxf(acc[mt][ct][0] + b1v[ct], 0.f);
                float h1 = fmaxf(acc[mt][ct][1] + b1v[ct], 0.f);
                float h2 = fmaxf(acc[mt][ct][2] + b1v[ct], 0.f);
                float h3 = fmaxf(acc[mt][ct][3] + b1v[ct], 0.f);
                p0 = fmaf(h0, w2v[ct], p0);
                p1 = fmaf(h1, w2v[ct], p1);
                p2 = fmaf(h2, w2v[ct], p2);
                p3 = fmaf(h3, w2v[ct], p3);
            }
            #pragma unroll
            for (int s = 1; s < 16; s <<= 1) {
                p0 += __shfl_xor(p0, s);
                p1 += __shfl_xor(p1, s);
                p2 += __shfl_xor(p2, s);
                p3 += __shfl_xor(p3, s);
            }
            const int myeid = __shfl(eidv, mt * 16 + lg * 4 + (lm & 3));
            if (lm < 4 && myeid >= 0) {
                const float pv = (lm & 2) ? ((lm & 1) ? p3 : p2)
                                          : ((lm & 1) ? p1 : p0);
                out[myeid] = 1.f / (1.f + __expf(-(pv + b2s)));
            }
        }

        if (!has) break;
        c = cn; i0v = i0n; i1v = i1n; eidv = eidn;
    }
}

extern "C" void kernel_launch(void* const* d_in, const int* in_sizes, int n_in,
                              void* d_out, int out_size, void* d_ws, size_t ws_size,
                              hipStream_t stream) {
    const float* left  = (const float*)d_in[0];
    const float* right = (const float*)d_in[1];
    const int*   pairs = (const int*)d_in[2];
    const float* W1    = (const float*)d_in[3];
    const float* b1    = (const float*)d_in[4];
    const float* W2    = (const float*)d_in[5];
    const float* b2    = (const float*)d_in[6];
    float* out = (float*)d_out;

    const int E  = in_sizes[2] / 2;                // pairs is [2][E]
    const int nn = in_sizes[0] / D;                // node count
    const int chunks = (E + CH - 1) / CH;
    const float scale = (float)NB / (float)nn;

    char* const ws = (char*)d_ws;
    const size_t offL   = 32768;
    const size_t szL    = (size_t)in_sizes[0] * 2;
    const size_t offR   = offL + szL;
    const size_t szR    = (size_t)in_sizes[1] * 2;
    const size_t offCnt = offR + szR;
    const size_t offBas = offCnt + (size_t)NB * 4;
    const size_t offRec = offBas + (size_t)SBLK * NB * 4;
    const size_t needSort = offRec + (size_t)chunks * CH * 16;
    const size_t needBf   = offCnt;

    short* const w1img  = (short*)ws;
    short* const leftb  = (short*)(ws + offL);
    short* const rightb = (short*)(ws + offR);
    int*   const counts = (int*)(ws + offCnt);
    int*   const bases  = (int*)(ws + offBas);
    int4*  const recs   = (int4*)(ws + offRec);

    prep_w1<<<64, 256, 0, stream>>>(W1, w1img);

    if (ws_size >= needSort) {
        hipMemsetAsync(counts, 0, NB * 4, stream);
        edge_histo<<<SBLK, 256, 0, stream>>>(pairs, E, scale, counts, bases);
        bucket_scan<<<1, 512, 0, stream>>>(counts);
        scatter_conv<<<SBLK + CONVB, 256, 0, stream>>>(
            pairs, E, scale, counts, bases, recs,
            left, right, leftb, rightb, in_sizes[0] / 8, in_sizes[1] / 8, SBLK);
        edge_decoder_kernel<2><<<512, BLK, 0, stream>>>(
            left, right, leftb, rightb, pairs, recs, w1img, b1, W2, b2, out, E);
    } else if (ws_size >= needBf) {
        scatter_conv<<<CONVB, 256, 0, stream>>>(
            pairs, E, scale, counts, bases, recs,
            left, right, leftb, rightb, in_sizes[0] / 8, in_sizes[1] / 8, 0);
        int blocks = 512;
        const int need = (chunks + WPB - 1) / WPB;
        if (need < blocks) blocks = need;
        edge_decoder_kernel<1><<<blocks, BLK, 0, stream>>>(
            left, right, leftb, rightb, pairs, recs, w1img, b1, W2, b2, out, E);
    } else {
        int blocks = 512;
        const int need = (chunks + WPB - 1) / WPB;
        if (need < blocks) blocks = need;
        edge_decoder_kernel<0><<<blocks, BLK, 0, stream>>>(
            left, right, leftb, rightb, pairs, recs, w1img, b1, W2, b2, out, E);
    }
}

// Round 10
// 106.560 us; speedup vs baseline: 3.1316x; 1.4921x over previous
//
#include <hip/hip_runtime.h>
#include <hip/hip_bf16.h>

typedef short bf16x8 __attribute__((ext_vector_type(8)));
typedef short short8 __attribute__((ext_vector_type(8)));
typedef float f32x4  __attribute__((ext_vector_type(4)));

#define D     128
#define CH    16          // edges per wave-chunk (wave-private staging)
#define WAVES 8           // waves per block
#define BLK   (WAVES*64)  // 512 threads
#define W1B   64          // prep blocks building the W1^T image
#define CONVB 2048        // prep blocks converting tables

// f32 -> bf16 round-to-nearest-even (finite inputs)
__device__ __forceinline__ short f2bf(float f) {
    unsigned u = __float_as_uint(f);
    u = (u + 0x7fffu + ((u >> 16) & 1u)) >> 16;
    return (short)u;
}
__device__ __forceinline__ float bf2f(short s) {
    return __uint_as_float(((unsigned)(unsigned short)s) << 16);
}

// LDS byte offset for [row][128 bf16], XOR-swizzled (16B-granular, G4).
__device__ __forceinline__ int swz(int row, int intra) {
    return (row << 8) + (intra ^ ((row & 7) << 4));
}

// Fused prep, ONE dispatch: blocks [0,W1B) build the swizzled W1^T bf16 LDS
// image (so main's staging is a linear conflict-free copy); blocks
// [W1B,W1B+CONVB) convert both node tables f32 -> bf16 (halves gather bytes).
// NT loads: the f32 sources are never re-read — don't let them churn L2/L3
// where the bf16 tables need to live.
__global__ __launch_bounds__(256)
void prep_fused(const float* __restrict__ W1, short* __restrict__ w1img,
                const float* __restrict__ l, const float* __restrict__ r,
                short* __restrict__ lb, short* __restrict__ rb,
                int n8l, int n8r) {
    if ((int)blockIdx.x < W1B) {
        const int idx = blockIdx.x * 256 + threadIdx.x;   // 64x256 = 16384
        const int k = idx >> 7, c = idx & 127;            // W1 is [k][c]
        w1img[((c << 8) + ((2 * k) ^ ((c & 7) << 4))) >> 1] = f2bf(W1[idx]);
    } else {
        int i = (blockIdx.x - W1B) * 256 + threadIdx.x;
        const int tot = n8l + n8r;
        for (; i < tot; i += CONVB * 256) {
            const float* s; short* d; int j;
            if (i < n8l) { s = l; d = lb; j = i; }
            else         { s = r; d = rb; j = i - n8l; }
            const f32x4 a = __builtin_nontemporal_load((const f32x4*)s + 2 * j);
            const f32x4 b = __builtin_nontemporal_load((const f32x4*)s + 2 * j + 1);
            short8 o;
            o[0]=f2bf(a[0]); o[1]=f2bf(a[1]); o[2]=f2bf(a[2]); o[3]=f2bf(a[3]);
            o[4]=f2bf(b[0]); o[5]=f2bf(b[1]); o[6]=f2bf(b[2]); o[7]=f2bf(b[3]);
            ((short8*)d)[j] = o;
        }
    }
}

// Main kernel (r6-proven structure). LDS: 32 KB W1^T + 8 waves x 4 KB
// wave-private x-stage = 64 KB -> 2 blocks/CU = 16 waves/CU.
// Gather: whole-row single-instruction reads in a tight burst (r3/r8 lesson:
// never spread one row's bytes across instructions/time — L2 reuse dies).
// MODE 0: f32 tables, W1 staged in-kernel (no-workspace fallback).
// MODE 1: bf16 tables + W1 image from d_ws.
template <int MODE>
__global__ __launch_bounds__(BLK, 4)
void edge_decoder_kernel(const float* __restrict__ left,
                         const float* __restrict__ right,
                         const short* __restrict__ leftb,
                         const short* __restrict__ rightb,
                         const int* __restrict__ pairs,
                         const short* __restrict__ w1ws,
                         const float* __restrict__ W1,
                         const float* __restrict__ b1,
                         const float* __restrict__ W2,
                         const float* __restrict__ b2,
                         float* __restrict__ out, int E)
{
    __shared__ char smem[65536];
    char* const w1t = smem;                                     // 32 KB
    char* const xls = smem + 32768 + (threadIdx.x >> 6) * 4096; // wave-private

    const int tid  = threadIdx.x;
    const int lane = tid & 63;
    const int wid  = tid >> 6;
    const int lg   = lane >> 4;       // lanegroup 0..3
    const int lm   = lane & 15;
    const int half = lane >> 5;       // 0: pairs0 / even edges, 1: pairs1 / odd
    const int l32  = lane & 31;

    // ---- Phase 0: W1^T -> LDS ----
    if (MODE == 1) {
        for (int j = tid; j < 2048; j += BLK)       // linear, conflict-free
            *(f32x4*)(w1t + j * 16) = ((const f32x4*)w1ws)[j];
    } else {
        for (int j = tid; j < 16384; j += BLK) {    // scatter staging (fallback)
            int k = j >> 7, c = j & 127;
            *(short*)(w1t + swz(c, 2 * k)) = f2bf(W1[j]);
        }
    }

    // per-lane slices of b1 / W2 (col = ct*16 + lm matches C-frag layout)
    float b1v[8], w2v[8];
    #pragma unroll
    for (int ct = 0; ct < 8; ++ct) {
        b1v[ct] = b1[ct * 16 + lm];
        w2v[ct] = W2[ct * 16 + lm];
    }
    const float b2s = b2[0];

    __syncthreads();                          // W1^T ready (only barrier)

    const int chunks = (E + CH - 1) / CH;
    const int stride = gridDim.x * WAVES;     // chunk-stride in wave units

    int c = blockIdx.x * WAVES + wid;
    if (c >= chunks) return;

    // index layout per chunk: lanes 0-15 hold pairs0[base+lm],
    // lanes 32-47 hold pairs1[base+lm] (lanes 16-31/48-63 duplicate).
    auto load_idx = [&](int cc) {
        int e0 = cc * CH + lm;
        if (e0 >= E) e0 = E - 1;              // tail clamp: safe gather
        return pairs[half * E + e0];
    };

    int idxv = load_idx(c);

    while (true) {
        const int cn = c + stride;
        const int base = c * CH;
        // prefetch next chunk's indices; latency hides under MFMA/epilogue
        const int idxv_n = (cn < chunks) ? load_idx(cn) : 0;

        if (MODE == 1) {
            // bf16 gather: 16B/lane, 16 lanes/row -> 4 whole rows per
            // instruction, 8 instructions per chunk, tight burst
            const int q  = lane >> 4;         // quarter 0..3 -> edge 4j+q
            const int lq = lane & 15;         // channels [8*lq, 8*lq+8)
            short8 lv[4], rv[4];
            #pragma unroll
            for (int j = 0; j < 4; ++j) {
                const int iL = __shfl(idxv, 4 * j + q);
                lv[j] = *(const short8*)(leftb + iL * D + lq * 8);
            }
            #pragma unroll
            for (int j = 0; j < 4; ++j) {
                const int iR = __shfl(idxv, 32 + 4 * j + q);
                rv[j] = *(const short8*)(rightb + iR * D + lq * 8);
            }
            #pragma unroll
            for (int j = 0; j < 4; ++j) {
                short8 xb;
                #pragma unroll
                for (int e = 0; e < 8; ++e)
                    xb[e] = f2bf(bf2f(lv[j][e]) * bf2f(rv[j][e]));
                *(short8*)(xls + swz(4 * j + q, lq * 16)) = xb;
            }
        } else {
            // f32 gather (fallback): whole-row float4 reads, burst
            float4 lv[8], rv[8];
            #pragma unroll
            for (int j = 0; j < 8; ++j) {
                const int eoff = 2 * j + half;
                const int iL = __shfl(idxv, eoff);
                const int iR = __shfl(idxv, 32 + eoff);
                lv[j] = *(const float4*)(left  + iL * D + l32 * 4);
                rv[j] = *(const float4*)(right + iR * D + l32 * 4);
            }
            #pragma unroll
            for (int j = 0; j < 8; ++j) {
                const int eoff = 2 * j + half;
                short4 xb;
                xb.x = f2bf(lv[j].x * rv[j].x);
                xb.y = f2bf(lv[j].y * rv[j].y);
                xb.z = f2bf(lv[j].z * rv[j].z);
                xb.w = f2bf(lv[j].w * rv[j].w);
                *(short4*)(xls + swz(eoff, l32 * 8)) = xb;
            }
        }

        // ---- MFMA: A and B share the same k-mapping (K-perm invariant) ----
        bf16x8 afr[4];
        #pragma unroll
        for (int kt = 0; kt < 4; ++kt)
            afr[kt] = *(const bf16x8*)(xls + swz(lm, kt * 64 + lg * 16));

        f32x4 acc[8];
        #pragma unroll
        for (int ct = 0; ct < 8; ++ct) acc[ct] = (f32x4){0.f, 0.f, 0.f, 0.f};

        #pragma unroll
        for (int kt = 0; kt < 4; ++kt)
            #pragma unroll
            for (int ct = 0; ct < 8; ++ct) {
                const bf16x8 bfr = *(const bf16x8*)(
                    w1t + swz(ct * 16 + lm, kt * 64 + lg * 16));
                acc[ct] = __builtin_amdgcn_mfma_f32_16x16x32_bf16(
                    afr[kt], bfr, acc[ct], 0, 0, 0);
            }

        // ---- bias + ReLU + dot(W2) + 16-lane reduce + sigmoid ----
        // C-frag layout (HW-measured): col = lane&15, row = (lane>>4)*4 + reg.
        float p0 = 0.f, p1 = 0.f, p2 = 0.f, p3 = 0.f;
        #pragma unroll
        for (int ct = 0; ct < 8; ++ct) {
            float h0 = fmaxf(acc[ct][0] + b1v[ct], 0.f);
            float h1 = fmaxf(acc[ct][1] + b1v[ct], 0.f);
            float h2 = fmaxf(acc[ct][2] + b1v[ct], 0.f);
            float h3 = fmaxf(acc[ct][3] + b1v[ct], 0.f);
            p0 = fmaf(h0, w2v[ct], p0);
            p1 = fmaf(h1, w2v[ct], p1);
            p2 = fmaf(h2, w2v[ct], p2);
            p3 = fmaf(h3, w2v[ct], p3);
        }
        #pragma unroll
        for (int s = 1; s < 16; s <<= 1) {
            p0 += __shfl_xor(p0, s);
            p1 += __shfl_xor(p1, s);
            p2 += __shfl_xor(p2, s);
            p3 += __shfl_xor(p3, s);
        }
        if (lm < 4) {
            const float pv = (lm & 2) ? ((lm & 1) ? p3 : p2)
                                      : ((lm & 1) ? p1 : p0);
            const int e = base + lg * 4 + lm;   // row = lg*4 + reg
            if (e < E) out[e] = 1.f / (1.f + __expf(-(pv + b2s)));
        }

        if (cn >= chunks) break;
        c = cn;
        idxv = idxv_n;
    }
}

extern "C" void kernel_launch(void* const* d_in, const int* in_sizes, int n_in,
                              void* d_out, int out_size, void* d_ws, size_t ws_size,
                              hipStream_t stream) {
    const float* left  = (const float*)d_in[0];
    const float* right = (const float*)d_in[1];
    const int*   pairs = (const int*)d_in[2];
    const float* W1    = (const float*)d_in[3];
    const float* b1    = (const float*)d_in[4];
    const float* W2    = (const float*)d_in[5];
    const float* b2    = (const float*)d_in[6];
    float* out = (float*)d_out;

    const int E = in_sizes[2] / 2;                 // pairs is [2][E]
    const int chunks = (E + CH - 1) / CH;
    int blocks = 512;                              // 2 blocks/CU * 256 CU
    const int need = (chunks + WAVES - 1) / WAVES;
    if (need < blocks) blocks = need;

    short* const w1img  = (short*)d_ws;            // [0, 32 KB)
    short* const leftb  = w1img + 16384;
    short* const rightb = leftb + in_sizes[0];
    const size_t need_ws = 32768 + (size_t)(in_sizes[0] + in_sizes[1]) * 2;

    if (ws_size >= need_ws) {
        prep_fused<<<W1B + CONVB, 256, 0, stream>>>(
            W1, w1img, left, right, leftb, rightb,
            in_sizes[0] / 8, in_sizes[1] / 8);
        edge_decoder_kernel<1><<<blocks, BLK, 0, stream>>>(
            left, right, leftb, rightb, pairs, w1img, W1, b1, W2, b2, out, E);
    } else {
        edge_decoder_kernel<0><<<blocks, BLK, 0, stream>>>(
            left, right, leftb, rightb, pairs, w1img, W1, b1, W2, b2, out, E);
    }
}